// Round 11
// baseline (123.504 us; speedup 1.0000x reference)
//
#include <hip/hip_runtime.h>
#include <hip/hip_bf16.h>
#include <cstdint>

// MultiHeadAttention_76338748719257 — MI355X (gfx950). R11.
// attn = R9's verified 8-wave v8 (41.9us). GEMM experiments:
//   gemm_qkv: 256x128 tile (512thr, 8 waves 4Mx2N, 48KB LDS) — halves weight
//   panel re-reads (B traffic 192->96MB) and block count 768->384.
//   gemm_out: 128x128 tile (was 128x64) — 2x MFMA per staged B-byte.

typedef __bf16 bf16_t;
typedef bf16_t bf16x8 __attribute__((ext_vector_type(8)));
typedef bf16_t bf16x4 __attribute__((ext_vector_type(4)));
typedef float  f32x4  __attribute__((ext_vector_type(4)));
typedef float  f32x16 __attribute__((ext_vector_type(16)));
typedef unsigned int u32;
typedef u32 u32x2 __attribute__((ext_vector_type(2)));

#define MFMA16(a, b, c) __builtin_amdgcn_mfma_f32_16x16x32_bf16((a), (b), (c), 0, 0, 0)
#define MFMA32(a, b, c) __builtin_amdgcn_mfma_f32_32x32x16_bf16((a), (b), (c), 0, 0, 0)

#define GLOAD_LDS16(gptr, lptr)                                                      \
  __builtin_amdgcn_global_load_lds(                                                  \
      (const __attribute__((address_space(1))) void*)(gptr),                         \
      (__attribute__((address_space(3))) void*)(lptr), 16, 0, 0)

namespace {
constexpr int kS = 2048, kE = 1024, kD = 64;
constexpr int kM = 4096;
constexpr float kQScaleL2E = 0.03125f * 1.44269504088896f;  // (1/sqrt(E))*log2(e)
}

__device__ inline u32 pkbf(float a, float b) {
  u32 r;
  asm("v_cvt_pk_bf16_f32 %0, %1, %2" : "=v"(r) : "v"(a), "v"(b));
  return r;
}

__device__ inline bf16x8 make_pfrag(float v0, float v1, float v2, float v3,
                                    float v4, float v5, float v6, float v7) {
  u32 A0 = pkbf(v0, v1), A1 = pkbf(v2, v3);
  u32 B0 = pkbf(v4, v5), B1 = pkbf(v6, v7);
  u32x2 r0 = __builtin_amdgcn_permlane32_swap(A0, B0, false, false);
  u32x2 r1 = __builtin_amdgcn_permlane32_swap(A1, B1, false, false);
  union { u32 w[4]; bf16x8 v; } u;
  u.w[0] = r0[0]; u.w[1] = r1[0]; u.w[2] = r0[1]; u.w[3] = r1[1];
  return u.v;
}

__device__ inline float xhalf_sum(float x) {
  u32 xu = __builtin_bit_cast(u32, x);
  u32x2 r = __builtin_amdgcn_permlane32_swap(xu, xu, false, false);
  return __builtin_bit_cast(float, r[0]) + __builtin_bit_cast(float, r[1]);
}

// ---------------- fp32 -> bf16 convert (4 buffers per launch) ----------------
__global__ void cvt_batch(const float* __restrict__ s0, const float* __restrict__ s1,
                          const float* __restrict__ s2, const float* __restrict__ s3,
                          bf16_t* __restrict__ d0, bf16_t* __restrict__ d1,
                          bf16_t* __restrict__ d2, bf16_t* __restrict__ d3, int n4) {
  const float* s; bf16_t* d;
  switch (blockIdx.y) {
    case 0:  s = s0; d = d0; break;
    case 1:  s = s1; d = d1; break;
    case 2:  s = s2; d = d2; break;
    default: s = s3; d = d3; break;
  }
  int stride = gridDim.x * blockDim.x;
  for (int i = blockIdx.x * blockDim.x + threadIdx.x; i < n4; i += stride) {
    float4 v = reinterpret_cast<const float4*>(s)[i];
    bf16x4 o;
    o[0] = (bf16_t)v.x; o[1] = (bf16_t)v.y; o[2] = (bf16_t)v.z; o[3] = (bf16_t)v.w;
    reinterpret_cast<bf16x4*>(d)[i] = o;
  }
}

// ---------------- fused QKV projection GEMM: 256x128 tile, 512 threads --------
// grid (24, 16): region = x>>3 (Q/K/V), col-in-region = (x&7)*128, rows = y*256.
__global__ __launch_bounds__(512, 2)
void gemm_qkv(const bf16_t* __restrict__ qb, const bf16_t* __restrict__ kb,
              const bf16_t* __restrict__ vb, const bf16_t* __restrict__ W,
              const float* __restrict__ bq, const float* __restrict__ bk,
              const float* __restrict__ bv,
              bf16_t* __restrict__ Qp, bf16_t* __restrict__ Kp, bf16_t* __restrict__ Vp) {
  constexpr int K = kE, BK = 64;
  __shared__ __align__(16) bf16_t As[256 * BK];  // 32 KB
  __shared__ __align__(16) bf16_t Bs[128 * BK];  // 16 KB
  const int tid = threadIdx.x, lane = tid & 63, wave = tid >> 6;
  const int fr = lane & 15, fg = lane >> 4;
  const int region = blockIdx.x >> 3;
  const int bm = blockIdx.y * 256, bn = blockIdx.x * 128;
  const int bnl = (blockIdx.x & 7) * 128;
  const bf16_t* A = region == 0 ? qb : region == 1 ? kb : vb;
  const float* bias = region == 0 ? bq : region == 1 ? bk : bv;
  bf16_t* Cp = region == 0 ? Qp : region == 1 ? Kp : Vp;
  const float scale = region == 0 ? kQScaleL2E : 1.0f;
  const int wr = (wave >> 1) * 64, wc = (wave & 1) * 64;
  f32x4 acc[4][4] = {};
  for (int k0 = 0; k0 < K; k0 += BK) {
#pragma unroll
    for (int c = 0; c < 4; ++c) {  // A tile 256x64 = 32KB
      int lin = c * 512 + tid, row = lin >> 3, ch = lin & 7, sch = ch ^ (row & 7);
      GLOAD_LDS16(A + (size_t)(bm + row) * K + k0 + sch * 8, (char*)As + lin * 16);
    }
#pragma unroll
    for (int c = 0; c < 2; ++c) {  // B tile 128x64 = 16KB
      int lin = c * 512 + tid, row = lin >> 3, ch = lin & 7, sch = ch ^ (row & 7);
      GLOAD_LDS16(W + (size_t)(bn + row) * K + k0 + sch * 8, (char*)Bs + lin * 16);
    }
    __syncthreads();
#pragma unroll
    for (int kk = 0; kk < 2; ++kk) {
      bf16x8 af[4], bfv[4];
#pragma unroll
      for (int i = 0; i < 4; ++i) {
        int row = wr + i * 16 + fr;
        int ch = (kk * 4 + fg) ^ (row & 7);
        af[i] = *reinterpret_cast<const bf16x8*>((const char*)As + row * 128 + ch * 16);
      }
#pragma unroll
      for (int j = 0; j < 4; ++j) {
        int row = wc + j * 16 + fr;
        int ch = (kk * 4 + fg) ^ (row & 7);
        bfv[j] = *reinterpret_cast<const bf16x8*>((const char*)Bs + row * 128 + ch * 16);
      }
#pragma unroll
      for (int i = 0; i < 4; ++i)
#pragma unroll
        for (int j = 0; j < 4; ++j)
          acc[i][j] = MFMA16(af[i], bfv[j], acc[i][j]);
    }
    __syncthreads();
  }
#pragma unroll
  for (int i = 0; i < 4; ++i)
#pragma unroll
    for (int j = 0; j < 4; ++j) {
      int coll = bnl + wc + j * 16 + fr;
      float bvv = bias[coll];
#pragma unroll
      for (int r = 0; r < 4; ++r) {
        int row = bm + wr + i * 16 + fg * 4 + r;
        Cp[(size_t)row * kE + coll] = (bf16_t)((acc[i][j][r] + bvv) * scale);
      }
    }
}

// ---------------- final GEMM: 128x128 tile, fp32 out + bias ----------------
__global__ __launch_bounds__(256, 2)
void gemm_out(const bf16_t* __restrict__ A, const bf16_t* __restrict__ Bm,
              const float* __restrict__ bias, float* __restrict__ Cout) {
  constexpr int K = kE, BK = 64;
  __shared__ __align__(16) bf16_t As[128 * BK];
  __shared__ __align__(16) bf16_t Bs[128 * BK];
  const int tid = threadIdx.x, lane = tid & 63, wave = tid >> 6;
  const int fr = lane & 15, fg = lane >> 4;
  const int bm = blockIdx.y * 128, bn = blockIdx.x * 128;
  const int wr = (wave >> 1) * 64, wc = (wave & 1) * 64;
  f32x4 acc[4][4] = {};
  for (int k0 = 0; k0 < K; k0 += BK) {
#pragma unroll
    for (int c = 0; c < 4; ++c) {
      int lin = c * 256 + tid, row = lin >> 3, ch = lin & 7, sch = ch ^ (row & 7);
      GLOAD_LDS16(A + (size_t)(bm + row) * K + k0 + sch * 8, (char*)As + lin * 16);
    }
#pragma unroll
    for (int c = 0; c < 4; ++c) {
      int lin = c * 256 + tid, row = lin >> 3, ch = lin & 7, sch = ch ^ (row & 7);
      GLOAD_LDS16(Bm + (size_t)(bn + row) * K + k0 + sch * 8, (char*)Bs + lin * 16);
    }
    __syncthreads();
#pragma unroll
    for (int kk = 0; kk < 2; ++kk) {
      bf16x8 af[4], bfv[4];
#pragma unroll
      for (int i = 0; i < 4; ++i) {
        int row = wr + i * 16 + fr;
        int ch = (kk * 4 + fg) ^ (row & 7);
        af[i] = *reinterpret_cast<const bf16x8*>((const char*)As + row * 128 + ch * 16);
      }
#pragma unroll
      for (int j = 0; j < 4; ++j) {
        int row = wc + j * 16 + fr;
        int ch = (kk * 4 + fg) ^ (row & 7);
        bfv[j] = *reinterpret_cast<const bf16x8*>((const char*)Bs + row * 128 + ch * 16);
      }
#pragma unroll
      for (int i = 0; i < 4; ++i)
#pragma unroll
        for (int j = 0; j < 4; ++j)
          acc[i][j] = MFMA16(af[i], bfv[j], acc[i][j]);
    }
    __syncthreads();
  }
#pragma unroll
  for (int i = 0; i < 4; ++i)
#pragma unroll
    for (int j = 0; j < 4; ++j) {
      int col = bn + wc + j * 16 + fr;
      float bvv = bias[col];
#pragma unroll
      for (int r = 0; r < 4; ++r) {
        int row = bm + wr + i * 16 + fg * 4 + r;
        Cout[(size_t)row * kE + col] = acc[i][j][r] + bvv;
      }
    }
}

// ---------------- per-head V transpose (unchanged) ----------------
__global__ __launch_bounds__(256)
void vtranspose(const bf16_t* __restrict__ Vp, bf16_t* __restrict__ VpT) {
  __shared__ __align__(16) bf16_t T[256 * 64];
  const int tid = threadIdx.x;
  const size_t hb = (size_t)blockIdx.y * (kS * kD);
  const bf16_t* src = Vp + hb + (size_t)blockIdx.x * 256 * kD;
  bf16_t* dst = VpT + hb + blockIdx.x * 256;
#pragma unroll
  for (int c = 0; c < 8; ++c) {
    int lin = c * 256 + tid;
    int row = lin >> 3, ch = lin & 7;
    bf16x8 v = *reinterpret_cast<const bf16x8*>(src + row * kD + ch * 8);
    *reinterpret_cast<bf16x8*>((char*)T + row * 128 + ((ch ^ ((row >> 3) & 7)) * 16)) = v;
  }
  __syncthreads();
#pragma unroll
  for (int c = 0; c < 8; ++c) {
    int lin = c * 256 + tid;
    int d = lin >> 5, kc = lin & 31;
    bf16x8 o;
#pragma unroll
    for (int e = 0; e < 8; ++e) {
      int s = kc * 8 + e;
      o[e] = *reinterpret_cast<const bf16_t*>(
          (const char*)T + s * 128 + (((d >> 3) ^ ((s >> 3) & 7)) * 16) + (d & 7) * 2);
    }
    *reinterpret_cast<bf16x8*>(dst + (size_t)d * kS + kc * 8) = o;
  }
}

// ---------------- flash attention v8 (= R9, verified 41.9us) ----------------
__global__ __launch_bounds__(512, 2)
void attn_fwd(const bf16_t* __restrict__ Qp, const bf16_t* __restrict__ Kp,
              const bf16_t* __restrict__ VpT, bf16_t* __restrict__ Op) {
  __shared__ __align__(16) char smem[66560];
  const int tid = threadIdx.x, lane = tid & 63, wave = tid >> 6;
  const int ql = lane & 31, hi = lane >> 5;
  const int g = wave >> 2, ws = wave & 3;
  const int tg = tid & 255;
  const int newb = ((int)blockIdx.x & 7) * 32 + ((int)blockIdx.x >> 3);
  const int head = newb >> 3, qt = newb & 7;
  const size_t hbase = (size_t)head * (kS * kD);
  const int q0 = qt * 256 + ws * 64;
  char* const gbase = smem + g * 32768;
  const bf16_t* Kh = Kp + hbase + (size_t)(g * 1024) * kD;
  const bf16_t* Vh = VpT + hbase + g * 1024;

  bf16x8 qfA[4], qfB[4];
#pragma unroll
  for (int ct = 0; ct < 4; ++ct) {
    qfA[ct] = *reinterpret_cast<const bf16x8*>(
        Qp + hbase + (size_t)(q0 + ql) * kD + ct * 16 + hi * 8);
    qfB[ct] = *reinterpret_cast<const bf16x8*>(
        Qp + hbase + (size_t)(q0 + 32 + ql) * kD + ct * 16 + hi * 8);
  }

  float LpA = 0.0f, LpB = 0.0f;
  f32x16 oA0 = {}, oA1 = {}, oB0 = {}, oB1 = {};

  auto STAGE = [&](int kt) {
    const bf16_t* Kt = Kh + (size_t)kt * 64 * kD;
    const bf16_t* Vt = Vh + kt * 64;
    char* Kd = gbase + (kt & 1) * 16384;
    char* Vd = Kd + 8192;
#pragma unroll
    for (int c = 0; c < 2; ++c) {
      int lin = c * 256 + tg, row = lin >> 3, ch = lin & 7, sch = ch ^ (row & 7);
      GLOAD_LDS16(Kt + row * kD + sch * 8, Kd + lin * 16);
    }
#pragma unroll
    for (int c = 0; c < 2; ++c) {
      int lin = c * 256 + tg, row = lin >> 3, ch = lin & 7, sch = ch ^ (row & 7);
      GLOAD_LDS16(Vt + (size_t)row * kS + sch * 8, Vd + lin * 16);
    }
  };

  STAGE(0);
#pragma unroll 1
  for (int kt = 0; kt < 16; ++kt) {
    __syncthreads();
    const char* Kb = gbase + (kt & 1) * 16384;
    const char* Vb = Kb + 8192;
    if (kt + 1 < 16) STAGE(kt + 1);

    f32x16 sA0 = {}, sA1 = {}, sB0 = {}, sB1 = {};
    __builtin_amdgcn_s_setprio(1);
#pragma unroll
    for (int ct = 0; ct < 4; ++ct) {
      bf16x8 k0 = *reinterpret_cast<const bf16x8*>(
          Kb + ql * 128 + (((2 * ct + hi) ^ (ql & 7)) * 16));
      bf16x8 k1 = *reinterpret_cast<const bf16x8*>(
          Kb + (32 + ql) * 128 + (((2 * ct + hi) ^ (ql & 7)) * 16));
      sA0 = MFMA32(k0, qfA[ct], sA0);
      sA1 = MFMA32(k1, qfA[ct], sA1);
      sB0 = MFMA32(k0, qfB[ct], sB0);
      sB1 = MFMA32(k1, qfB[ct], sB1);
    }
    __builtin_amdgcn_s_setprio(0);

    float aA = 0.f, aB = 0.f;
#pragma unroll
    for (int r = 0; r < 16; ++r) {
      sA0[r] = __builtin_amdgcn_exp2f(sA0[r]);
      sA1[r] = __builtin_amdgcn_exp2f(sA1[r]);
      sB0[r] = __builtin_amdgcn_exp2f(sB0[r]);
      sB1[r] = __builtin_amdgcn_exp2f(sB1[r]);
      aA += sA0[r] + sA1[r];
      aB += sB0[r] + sB1[r];
    }
    LpA += aA; LpB += aB;

    bf16x8 pA0 = make_pfrag(sA0[0], sA0[1], sA0[2], sA0[3], sA0[4], sA0[5], sA0[6], sA0[7]);
    bf16x8 pA1 = make_pfrag(sA0[8], sA0[9], sA0[10], sA0[11], sA0[12], sA0[13], sA0[14], sA0[15]);
    bf16x8 pA2 = make_pfrag(sA1[0], sA1[1], sA1[2], sA1[3], sA1[4], sA1[5], sA1[6], sA1[7]);
    bf16x8 pA3 = make_pfrag(sA1[8], sA1[9], sA1[10], sA1[11], sA1[12], sA1[13], sA1[14], sA1[15]);
    bf16x8 pB0 = make_pfrag(sB0[0], sB0[1], sB0[2], sB0[3], sB0[4], sB0[5], sB0[6], sB0[7]);
    bf16x8 pB1 = make_pfrag(sB0[8], sB0[9], sB0[10], sB0[11], sB0[12], sB0[13], sB0[14], sB0[15]);
    bf16x8 pB2 = make_pfrag(sB1[0], sB1[1], sB1[2], sB1[3], sB1[4], sB1[5], sB1[6], sB1[7]);
    bf16x8 pB3 = make_pfrag(sB1[8], sB1[9], sB1[10], sB1[11], sB1[12], sB1[13], sB1[14], sB1[15]);

    __builtin_amdgcn_s_setprio(1);
#pragma unroll
    for (int j = 0; j < 4; ++j) {
      bf16x8 v0 = *reinterpret_cast<const bf16x8*>(
          Vb + ql * 128 + (((2 * j + hi) ^ (ql & 7)) * 16));
      bf16x8 v1 = *reinterpret_cast<const bf16x8*>(
          Vb + (32 + ql) * 128 + (((2 * j + hi) ^ (ql & 7)) * 16));
      bf16x8 pA = (j == 0) ? pA0 : (j == 1) ? pA1 : (j == 2) ? pA2 : pA3;
      bf16x8 pB = (j == 0) ? pB0 : (j == 1) ? pB1 : (j == 2) ? pB2 : pB3;
      oA0 = MFMA32(v0, pA, oA0);
      oA1 = MFMA32(v1, pA, oA1);
      oB0 = MFMA32(v0, pB, oB0);
      oB1 = MFMA32(v1, pB, oB1);
    }
    __builtin_amdgcn_s_setprio(0);
  }

  __syncthreads();
  if (g == 1) {
    char* pb = smem + ws * 16384;
#pragma unroll
    for (int c = 0; c < 4; ++c) {
      *reinterpret_cast<f32x4*>(pb + c * 1024 + lane * 16) =
          (f32x4){oA0[4 * c], oA0[4 * c + 1], oA0[4 * c + 2], oA0[4 * c + 3]};
      *reinterpret_cast<f32x4*>(pb + 4096 + c * 1024 + lane * 16) =
          (f32x4){oA1[4 * c], oA1[4 * c + 1], oA1[4 * c + 2], oA1[4 * c + 3]};
      *reinterpret_cast<f32x4*>(pb + 8192 + c * 1024 + lane * 16) =
          (f32x4){oB0[4 * c], oB0[4 * c + 1], oB0[4 * c + 2], oB0[4 * c + 3]};
      *reinterpret_cast<f32x4*>(pb + 12288 + c * 1024 + lane * 16) =
          (f32x4){oB1[4 * c], oB1[4 * c + 1], oB1[4 * c + 2], oB1[4 * c + 3]};
    }
    float LA = xhalf_sum(LpA), LB = xhalf_sum(LpB);
    if (hi == 0) {
      *reinterpret_cast<float*>(smem + 65536 + (ws * 64 + ql) * 4) = LA;
      *reinterpret_cast<float*>(smem + 65536 + (ws * 64 + 32 + ql) * 4) = LB;
    }
  }
  __syncthreads();
  if (g == 0) {
    const char* pb = smem + ws * 16384;
#pragma unroll
    for (int c = 0; c < 4; ++c) {
      f32x4 rA0 = *reinterpret_cast<const f32x4*>(pb + c * 1024 + lane * 16);
      f32x4 rA1 = *reinterpret_cast<const f32x4*>(pb + 4096 + c * 1024 + lane * 16);
      f32x4 rB0 = *reinterpret_cast<const f32x4*>(pb + 8192 + c * 1024 + lane * 16);
      f32x4 rB1 = *reinterpret_cast<const f32x4*>(pb + 12288 + c * 1024 + lane * 16);
#pragma unroll
      for (int i = 0; i < 4; ++i) {
        oA0[4 * c + i] += rA0[i]; oA1[4 * c + i] += rA1[i];
        oB0[4 * c + i] += rB0[i]; oB1[4 * c + i] += rB1[i];
      }
    }
    float LA = xhalf_sum(LpA) +
               *reinterpret_cast<const float*>(smem + 65536 + (ws * 64 + ql) * 4);
    float LB = xhalf_sum(LpB) +
               *reinterpret_cast<const float*>(smem + 65536 + (ws * 64 + 32 + ql) * 4);
    float invA = 1.0f / LA, invB = 1.0f / LB;
#pragma unroll
    for (int r = 0; r < 16; ++r) {
      oA0[r] *= invA; oA1[r] *= invA; oB0[r] *= invB; oB1[r] *= invB;
    }
#pragma unroll
    for (int X = 0; X < 2; ++X) {
      const int wb = ws * 16384 + X * 4096;
      const int qX = q0 + X * 32;
#pragma unroll
      for (int c = 0; c < 4; ++c) {
        float e00 = X ? oB0[4 * c + 0] : oA0[4 * c + 0];
        float e01 = X ? oB0[4 * c + 1] : oA0[4 * c + 1];
        float e02 = X ? oB0[4 * c + 2] : oA0[4 * c + 2];
        float e03 = X ? oB0[4 * c + 3] : oA0[4 * c + 3];
        float e10 = X ? oB1[4 * c + 0] : oA1[4 * c + 0];
        float e11 = X ? oB1[4 * c + 1] : oA1[4 * c + 1];
        float e12 = X ? oB1[4 * c + 2] : oA1[4 * c + 2];
        float e13 = X ? oB1[4 * c + 3] : oA1[4 * c + 3];
        {
          u32 w0 = pkbf(e00, e01), w1 = pkbf(e02, e03);
          int d0 = 8 * c + 4 * hi;
          int byte = (wb + ql * 128 + d0 * 2) ^ ((ql & 7) << 4);
          *reinterpret_cast<u32x2*>(smem + byte) = (u32x2){w0, w1};
        }
        {
          u32 w0 = pkbf(e10, e11), w1 = pkbf(e12, e13);
          int d0 = 32 + 8 * c + 4 * hi;
          int byte = (wb + ql * 128 + d0 * 2) ^ ((ql & 7) << 4);
          *reinterpret_cast<u32x2*>(smem + byte) = (u32x2){w0, w1};
        }
      }
      asm volatile("s_waitcnt lgkmcnt(0)" ::: "memory");
      __builtin_amdgcn_sched_barrier(0);
#pragma unroll
      for (int it = 0; it < 4; ++it) {
        int lin = it * 64 + lane;
        int qr = lin >> 3, ch = lin & 7;
        int byte = wb + qr * 128 + ((ch * 16) ^ ((qr & 7) << 4));
        bf16x8 vrow = *reinterpret_cast<const bf16x8*>(smem + byte);
        *reinterpret_cast<bf16x8*>(Op + hbase + (size_t)(qX + qr) * kD + ch * 8) = vrow;
      }
    }
  }
}

// ---------------- host launch ----------------
extern "C" void kernel_launch(void* const* d_in, const int* in_sizes, int n_in,
                              void* d_out, int out_size, void* d_ws, size_t ws_size,
                              hipStream_t stream) {
  (void)in_sizes; (void)n_in; (void)out_size; (void)ws_size;
  const float* q  = (const float*)d_in[0];
  const float* k  = (const float*)d_in[1];
  const float* v  = (const float*)d_in[2];
  const float* wq = (const float*)d_in[3];
  const float* bq = (const float*)d_in[4];
  const float* wk = (const float*)d_in[5];
  const float* bk = (const float*)d_in[6];
  const float* wv = (const float*)d_in[7];
  const float* bv = (const float*)d_in[8];
  const float* wo = (const float*)d_in[9];
  const float* bo = (const float*)d_in[10];
  float* out = (float*)d_out;

  char* ws = (char*)d_ws;
  const size_t MB = 1ull << 20;
  bf16_t* qb   = (bf16_t*)(ws +  0 * MB);
  bf16_t* kb   = (bf16_t*)(ws +  8 * MB);
  bf16_t* vb   = (bf16_t*)(ws + 16 * MB);
  bf16_t* wqkv = (bf16_t*)(ws + 24 * MB);
  bf16_t* wob  = (bf16_t*)(ws + 30 * MB);
  bf16_t* Qp   = (bf16_t*)(ws + 32 * MB);
  bf16_t* Kp   = (bf16_t*)(ws + 40 * MB);
  bf16_t* Vp   = (bf16_t*)(ws + 48 * MB);
  bf16_t* Opb  = (bf16_t*)(ws + 56 * MB);
  bf16_t* VpT  = (bf16_t*)(ws +  0 * MB);  // reuses qb (dead after projection)

  const int nQKV4 = (kM * kE) / 4;
  const int nW4 = (kE * kE) / 4;
  cvt_batch<<<dim3(512, 3), 256, 0, stream>>>(q, k, v, v, qb, kb, vb, vb, nQKV4);
  cvt_batch<<<dim3(128, 4), 256, 0, stream>>>(wq, wk, wv, wo, wqkv, wqkv + 1048576,
                                              wqkv + 2097152, wob, nW4);

  gemm_qkv<<<dim3(24, 16), 512, 0, stream>>>(qb, kb, vb, wqkv, bq, bk, bv, Qp, Kp, Vp);

  vtranspose<<<dim3(kS / 256, 32), 256, 0, stream>>>(Vp, VpT);

  attn_fwd<<<dim3(256), 512, 0, stream>>>(Qp, Kp, VpT, Opb);

  gemm_out<<<dim3(8, 32), 256, 0, stream>>>(Opb, wob, bo, out);
}

// Round 12
// 114.651 us; speedup vs baseline: 1.0772x; 1.0772x over previous
//
#include <hip/hip_runtime.h>
#include <hip/hip_bf16.h>
#include <cstdint>

// MultiHeadAttention_76338748719257 — MI355X (gfx950). R12.
// = R9 (verified best, 117.4us) with: (1) single merged cvt launch (7 buffers),
// (2) s_setprio removed from attn (lockstep 8-wave block = m190 null regime).
// GEMMs identical to R9 (R11's bigger tiles regressed -6us: block count >
// per-block reuse at these shapes).

typedef __bf16 bf16_t;
typedef bf16_t bf16x8 __attribute__((ext_vector_type(8)));
typedef bf16_t bf16x4 __attribute__((ext_vector_type(4)));
typedef float  f32x4  __attribute__((ext_vector_type(4)));
typedef float  f32x16 __attribute__((ext_vector_type(16)));
typedef unsigned int u32;
typedef u32 u32x2 __attribute__((ext_vector_type(2)));

#define MFMA16(a, b, c) __builtin_amdgcn_mfma_f32_16x16x32_bf16((a), (b), (c), 0, 0, 0)
#define MFMA32(a, b, c) __builtin_amdgcn_mfma_f32_32x32x16_bf16((a), (b), (c), 0, 0, 0)

#define GLOAD_LDS16(gptr, lptr)                                                      \
  __builtin_amdgcn_global_load_lds(                                                  \
      (const __attribute__((address_space(1))) void*)(gptr),                         \
      (__attribute__((address_space(3))) void*)(lptr), 16, 0, 0)

namespace {
constexpr int kS = 2048, kE = 1024, kD = 64;
constexpr int kM = 4096;
constexpr float kQScaleL2E = 0.03125f * 1.44269504088896f;  // (1/sqrt(E))*log2(e)
}

__device__ inline u32 pkbf(float a, float b) {
  u32 r;
  asm("v_cvt_pk_bf16_f32 %0, %1, %2" : "=v"(r) : "v"(a), "v"(b));
  return r;
}

__device__ inline bf16x8 make_pfrag(float v0, float v1, float v2, float v3,
                                    float v4, float v5, float v6, float v7) {
  u32 A0 = pkbf(v0, v1), A1 = pkbf(v2, v3);
  u32 B0 = pkbf(v4, v5), B1 = pkbf(v6, v7);
  u32x2 r0 = __builtin_amdgcn_permlane32_swap(A0, B0, false, false);
  u32x2 r1 = __builtin_amdgcn_permlane32_swap(A1, B1, false, false);
  union { u32 w[4]; bf16x8 v; } u;
  u.w[0] = r0[0]; u.w[1] = r1[0]; u.w[2] = r0[1]; u.w[3] = r1[1];
  return u.v;
}

__device__ inline float xhalf_sum(float x) {
  u32 xu = __builtin_bit_cast(u32, x);
  u32x2 r = __builtin_amdgcn_permlane32_swap(xu, xu, false, false);
  return __builtin_bit_cast(float, r[0]) + __builtin_bit_cast(float, r[1]);
}

// ---------------- fp32 -> bf16 convert: ALL 7 buffers in one launch ----------
__global__ void cvt_all(const float* __restrict__ q, const float* __restrict__ k,
                        const float* __restrict__ v, const float* __restrict__ wq,
                        const float* __restrict__ wk, const float* __restrict__ wv,
                        const float* __restrict__ wo,
                        bf16_t* __restrict__ qb, bf16_t* __restrict__ kb,
                        bf16_t* __restrict__ vb, bf16_t* __restrict__ wqkvb,
                        bf16_t* __restrict__ wob) {
  const float* s; bf16_t* d; int n4;
  switch (blockIdx.y) {
    case 0: s = q;  d = qb;             n4 = 1048576; break;
    case 1: s = k;  d = kb;             n4 = 1048576; break;
    case 2: s = v;  d = vb;             n4 = 1048576; break;
    case 3: s = wq; d = wqkvb;          n4 = 262144;  break;
    case 4: s = wk; d = wqkvb + 1048576; n4 = 262144; break;
    case 5: s = wv; d = wqkvb + 2097152; n4 = 262144; break;
    default: s = wo; d = wob;           n4 = 262144;  break;
  }
  int stride = gridDim.x * blockDim.x;
  for (int i = blockIdx.x * blockDim.x + threadIdx.x; i < n4; i += stride) {
    float4 vv = reinterpret_cast<const float4*>(s)[i];
    bf16x4 o;
    o[0] = (bf16_t)vv.x; o[1] = (bf16_t)vv.y; o[2] = (bf16_t)vv.z; o[3] = (bf16_t)vv.w;
    reinterpret_cast<bf16x4*>(d)[i] = o;
  }
}

// ---------------- fused QKV projection GEMM (= R9) ----------------
__global__ __launch_bounds__(256, 3)
void gemm_qkv(const bf16_t* __restrict__ qb, const bf16_t* __restrict__ kb,
              const bf16_t* __restrict__ vb, const bf16_t* __restrict__ W,
              const float* __restrict__ bq, const float* __restrict__ bk,
              const float* __restrict__ bv,
              bf16_t* __restrict__ Qp, bf16_t* __restrict__ Kp, bf16_t* __restrict__ Vp) {
  constexpr int K = kE, BK = 64;
  __shared__ __align__(16) bf16_t As[128 * BK];
  __shared__ __align__(16) bf16_t Bs[128 * BK];
  const int tid = threadIdx.x, lane = tid & 63, wave = tid >> 6;
  const int fr = lane & 15, fg = lane >> 4;
  const int region = blockIdx.x >> 3;
  const int bm = blockIdx.y * 128, bn = blockIdx.x * 128;
  const int bnl = (blockIdx.x & 7) * 128;
  const bf16_t* A = region == 0 ? qb : region == 1 ? kb : vb;
  const float* bias = region == 0 ? bq : region == 1 ? bk : bv;
  bf16_t* Cp = region == 0 ? Qp : region == 1 ? Kp : Vp;
  const float scale = region == 0 ? kQScaleL2E : 1.0f;
  const int wr = (wave >> 1) * 64, wc = (wave & 1) * 64;
  f32x4 acc[4][4] = {};
  for (int k0 = 0; k0 < K; k0 += BK) {
#pragma unroll
    for (int c = 0; c < 4; ++c) {
      int lin = c * 256 + tid, row = lin >> 3, ch = lin & 7, sch = ch ^ (row & 7);
      GLOAD_LDS16(A + (size_t)(bm + row) * K + k0 + sch * 8, (char*)As + lin * 16);
    }
#pragma unroll
    for (int c = 0; c < 4; ++c) {
      int lin = c * 256 + tid, row = lin >> 3, ch = lin & 7, sch = ch ^ (row & 7);
      GLOAD_LDS16(W + (size_t)(bn + row) * K + k0 + sch * 8, (char*)Bs + lin * 16);
    }
    __syncthreads();
#pragma unroll
    for (int kk = 0; kk < 2; ++kk) {
      bf16x8 af[4], bfv[4];
#pragma unroll
      for (int i = 0; i < 4; ++i) {
        int row = wr + i * 16 + fr;
        int ch = (kk * 4 + fg) ^ (row & 7);
        af[i] = *reinterpret_cast<const bf16x8*>((const char*)As + row * 128 + ch * 16);
      }
#pragma unroll
      for (int j = 0; j < 4; ++j) {
        int row = wc + j * 16 + fr;
        int ch = (kk * 4 + fg) ^ (row & 7);
        bfv[j] = *reinterpret_cast<const bf16x8*>((const char*)Bs + row * 128 + ch * 16);
      }
#pragma unroll
      for (int i = 0; i < 4; ++i)
#pragma unroll
        for (int j = 0; j < 4; ++j)
          acc[i][j] = MFMA16(af[i], bfv[j], acc[i][j]);
    }
    __syncthreads();
  }
#pragma unroll
  for (int i = 0; i < 4; ++i)
#pragma unroll
    for (int j = 0; j < 4; ++j) {
      int coll = bnl + wc + j * 16 + fr;
      float bvv = bias[coll];
#pragma unroll
      for (int r = 0; r < 4; ++r) {
        int row = bm + wr + i * 16 + fg * 4 + r;
        Cp[(size_t)row * kE + coll] = (bf16_t)((acc[i][j][r] + bvv) * scale);
      }
    }
}

// ---------------- final GEMM (= R9) ----------------
__global__ __launch_bounds__(256, 3)
void gemm_out(const bf16_t* __restrict__ A, const bf16_t* __restrict__ Bm,
              const float* __restrict__ bias, float* __restrict__ Cout) {
  constexpr int K = kE, BK = 64;
  __shared__ __align__(16) bf16_t As[128 * BK];
  __shared__ __align__(16) bf16_t Bs[64 * BK];
  const int tid = threadIdx.x, lane = tid & 63, wave = tid >> 6;
  const int fr = lane & 15, fg = lane >> 4;
  const int bm = blockIdx.y * 128, bn = blockIdx.x * 64;
  const int wr = wave * 32;
  f32x4 acc[2][4] = {};
  for (int k0 = 0; k0 < K; k0 += BK) {
#pragma unroll
    for (int c = 0; c < 4; ++c) {
      int lin = c * 256 + tid, row = lin >> 3, ch = lin & 7, sch = ch ^ (row & 7);
      GLOAD_LDS16(A + (size_t)(bm + row) * K + k0 + sch * 8, (char*)As + lin * 16);
    }
#pragma unroll
    for (int c = 0; c < 2; ++c) {
      int lin = c * 256 + tid, row = lin >> 3, ch = lin & 7, sch = ch ^ (row & 7);
      GLOAD_LDS16(Bm + (size_t)(bn + row) * K + k0 + sch * 8, (char*)Bs + lin * 16);
    }
    __syncthreads();
#pragma unroll
    for (int kk = 0; kk < 2; ++kk) {
      bf16x8 af[2], bfv[4];
#pragma unroll
      for (int i = 0; i < 2; ++i) {
        int row = wr + i * 16 + fr;
        int ch = (kk * 4 + fg) ^ (row & 7);
        af[i] = *reinterpret_cast<const bf16x8*>((const char*)As + row * 128 + ch * 16);
      }
#pragma unroll
      for (int j = 0; j < 4; ++j) {
        int row = j * 16 + fr;
        int ch = (kk * 4 + fg) ^ (row & 7);
        bfv[j] = *reinterpret_cast<const bf16x8*>((const char*)Bs + row * 128 + ch * 16);
      }
#pragma unroll
      for (int i = 0; i < 2; ++i)
#pragma unroll
        for (int j = 0; j < 4; ++j)
          acc[i][j] = MFMA16(af[i], bfv[j], acc[i][j]);
    }
    __syncthreads();
  }
#pragma unroll
  for (int i = 0; i < 2; ++i)
#pragma unroll
    for (int j = 0; j < 4; ++j) {
      int col = bn + j * 16 + fr;
      float bvv = bias[col];
#pragma unroll
      for (int r = 0; r < 4; ++r) {
        int row = bm + wr + i * 16 + fg * 4 + r;
        Cout[(size_t)row * kE + col] = acc[i][j][r] + bvv;
      }
    }
}

// ---------------- per-head V transpose (= R9) ----------------
__global__ __launch_bounds__(256)
void vtranspose(const bf16_t* __restrict__ Vp, bf16_t* __restrict__ VpT) {
  __shared__ __align__(16) bf16_t T[256 * 64];
  const int tid = threadIdx.x;
  const size_t hb = (size_t)blockIdx.y * (kS * kD);
  const bf16_t* src = Vp + hb + (size_t)blockIdx.x * 256 * kD;
  bf16_t* dst = VpT + hb + blockIdx.x * 256;
#pragma unroll
  for (int c = 0; c < 8; ++c) {
    int lin = c * 256 + tid;
    int row = lin >> 3, ch = lin & 7;
    bf16x8 v = *reinterpret_cast<const bf16x8*>(src + row * kD + ch * 8);
    *reinterpret_cast<bf16x8*>((char*)T + row * 128 + ((ch ^ ((row >> 3) & 7)) * 16)) = v;
  }
  __syncthreads();
#pragma unroll
  for (int c = 0; c < 8; ++c) {
    int lin = c * 256 + tid;
    int d = lin >> 5, kc = lin & 31;
    bf16x8 o;
#pragma unroll
    for (int e = 0; e < 8; ++e) {
      int s = kc * 8 + e;
      o[e] = *reinterpret_cast<const bf16_t*>(
          (const char*)T + s * 128 + (((d >> 3) ^ ((s >> 3) & 7)) * 16) + (d & 7) * 2);
    }
    *reinterpret_cast<bf16x8*>(dst + (size_t)d * kS + kc * 8) = o;
  }
}

// ---------------- flash attention v8 (= R9, setprio removed) ----------------
__global__ __launch_bounds__(512, 2)
void attn_fwd(const bf16_t* __restrict__ Qp, const bf16_t* __restrict__ Kp,
              const bf16_t* __restrict__ VpT, bf16_t* __restrict__ Op) {
  __shared__ __align__(16) char smem[66560];
  const int tid = threadIdx.x, lane = tid & 63, wave = tid >> 6;
  const int ql = lane & 31, hi = lane >> 5;
  const int g = wave >> 2, ws = wave & 3;
  const int tg = tid & 255;
  const int newb = ((int)blockIdx.x & 7) * 32 + ((int)blockIdx.x >> 3);
  const int head = newb >> 3, qt = newb & 7;
  const size_t hbase = (size_t)head * (kS * kD);
  const int q0 = qt * 256 + ws * 64;
  char* const gbase = smem + g * 32768;
  const bf16_t* Kh = Kp + hbase + (size_t)(g * 1024) * kD;
  const bf16_t* Vh = VpT + hbase + g * 1024;

  bf16x8 qfA[4], qfB[4];
#pragma unroll
  for (int ct = 0; ct < 4; ++ct) {
    qfA[ct] = *reinterpret_cast<const bf16x8*>(
        Qp + hbase + (size_t)(q0 + ql) * kD + ct * 16 + hi * 8);
    qfB[ct] = *reinterpret_cast<const bf16x8*>(
        Qp + hbase + (size_t)(q0 + 32 + ql) * kD + ct * 16 + hi * 8);
  }

  float LpA = 0.0f, LpB = 0.0f;
  f32x16 oA0 = {}, oA1 = {}, oB0 = {}, oB1 = {};

  auto STAGE = [&](int kt) {
    const bf16_t* Kt = Kh + (size_t)kt * 64 * kD;
    const bf16_t* Vt = Vh + kt * 64;
    char* Kd = gbase + (kt & 1) * 16384;
    char* Vd = Kd + 8192;
#pragma unroll
    for (int c = 0; c < 2; ++c) {
      int lin = c * 256 + tg, row = lin >> 3, ch = lin & 7, sch = ch ^ (row & 7);
      GLOAD_LDS16(Kt + row * kD + sch * 8, Kd + lin * 16);
    }
#pragma unroll
    for (int c = 0; c < 2; ++c) {
      int lin = c * 256 + tg, row = lin >> 3, ch = lin & 7, sch = ch ^ (row & 7);
      GLOAD_LDS16(Vt + (size_t)row * kS + sch * 8, Vd + lin * 16);
    }
  };

  STAGE(0);
#pragma unroll 1
  for (int kt = 0; kt < 16; ++kt) {
    __syncthreads();
    const char* Kb = gbase + (kt & 1) * 16384;
    const char* Vb = Kb + 8192;
    if (kt + 1 < 16) STAGE(kt + 1);

    f32x16 sA0 = {}, sA1 = {}, sB0 = {}, sB1 = {};
#pragma unroll
    for (int ct = 0; ct < 4; ++ct) {
      bf16x8 k0 = *reinterpret_cast<const bf16x8*>(
          Kb + ql * 128 + (((2 * ct + hi) ^ (ql & 7)) * 16));
      bf16x8 k1 = *reinterpret_cast<const bf16x8*>(
          Kb + (32 + ql) * 128 + (((2 * ct + hi) ^ (ql & 7)) * 16));
      sA0 = MFMA32(k0, qfA[ct], sA0);
      sA1 = MFMA32(k1, qfA[ct], sA1);
      sB0 = MFMA32(k0, qfB[ct], sB0);
      sB1 = MFMA32(k1, qfB[ct], sB1);
    }

    float aA = 0.f, aB = 0.f;
#pragma unroll
    for (int r = 0; r < 16; ++r) {
      sA0[r] = __builtin_amdgcn_exp2f(sA0[r]);
      sA1[r] = __builtin_amdgcn_exp2f(sA1[r]);
      sB0[r] = __builtin_amdgcn_exp2f(sB0[r]);
      sB1[r] = __builtin_amdgcn_exp2f(sB1[r]);
      aA += sA0[r] + sA1[r];
      aB += sB0[r] + sB1[r];
    }
    LpA += aA; LpB += aB;

    bf16x8 pA0 = make_pfrag(sA0[0], sA0[1], sA0[2], sA0[3], sA0[4], sA0[5], sA0[6], sA0[7]);
    bf16x8 pA1 = make_pfrag(sA0[8], sA0[9], sA0[10], sA0[11], sA0[12], sA0[13], sA0[14], sA0[15]);
    bf16x8 pA2 = make_pfrag(sA1[0], sA1[1], sA1[2], sA1[3], sA1[4], sA1[5], sA1[6], sA1[7]);
    bf16x8 pA3 = make_pfrag(sA1[8], sA1[9], sA1[10], sA1[11], sA1[12], sA1[13], sA1[14], sA1[15]);
    bf16x8 pB0 = make_pfrag(sB0[0], sB0[1], sB0[2], sB0[3], sB0[4], sB0[5], sB0[6], sB0[7]);
    bf16x8 pB1 = make_pfrag(sB0[8], sB0[9], sB0[10], sB0[11], sB0[12], sB0[13], sB0[14], sB0[15]);
    bf16x8 pB2 = make_pfrag(sB1[0], sB1[1], sB1[2], sB1[3], sB1[4], sB1[5], sB1[6], sB1[7]);
    bf16x8 pB3 = make_pfrag(sB1[8], sB1[9], sB1[10], sB1[11], sB1[12], sB1[13], sB1[14], sB1[15]);

#pragma unroll
    for (int j = 0; j < 4; ++j) {
      bf16x8 v0 = *reinterpret_cast<const bf16x8*>(
          Vb + ql * 128 + (((2 * j + hi) ^ (ql & 7)) * 16));
      bf16x8 v1 = *reinterpret_cast<const bf16x8*>(
          Vb + (32 + ql) * 128 + (((2 * j + hi) ^ (ql & 7)) * 16));
      bf16x8 pA = (j == 0) ? pA0 : (j == 1) ? pA1 : (j == 2) ? pA2 : pA3;
      bf16x8 pB = (j == 0) ? pB0 : (j == 1) ? pB1 : (j == 2) ? pB2 : pB3;
      oA0 = MFMA32(v0, pA, oA0);
      oA1 = MFMA32(v1, pA, oA1);
      oB0 = MFMA32(v0, pB, oB0);
      oB1 = MFMA32(v1, pB, oB1);
    }
  }

  __syncthreads();
  if (g == 1) {
    char* pb = smem + ws * 16384;
#pragma unroll
    for (int c = 0; c < 4; ++c) {
      *reinterpret_cast<f32x4*>(pb + c * 1024 + lane * 16) =
          (f32x4){oA0[4 * c], oA0[4 * c + 1], oA0[4 * c + 2], oA0[4 * c + 3]};
      *reinterpret_cast<f32x4*>(pb + 4096 + c * 1024 + lane * 16) =
          (f32x4){oA1[4 * c], oA1[4 * c + 1], oA1[4 * c + 2], oA1[4 * c + 3]};
      *reinterpret_cast<f32x4*>(pb + 8192 + c * 1024 + lane * 16) =
          (f32x4){oB0[4 * c], oB0[4 * c + 1], oB0[4 * c + 2], oB0[4 * c + 3]};
      *reinterpret_cast<f32x4*>(pb + 12288 + c * 1024 + lane * 16) =
          (f32x4){oB1[4 * c], oB1[4 * c + 1], oB1[4 * c + 2], oB1[4 * c + 3]};
    }
    float LA = xhalf_sum(LpA), LB = xhalf_sum(LpB);
    if (hi == 0) {
      *reinterpret_cast<float*>(smem + 65536 + (ws * 64 + ql) * 4) = LA;
      *reinterpret_cast<float*>(smem + 65536 + (ws * 64 + 32 + ql) * 4) = LB;
    }
  }
  __syncthreads();
  if (g == 0) {
    const char* pb = smem + ws * 16384;
#pragma unroll
    for (int c = 0; c < 4; ++c) {
      f32x4 rA0 = *reinterpret_cast<const f32x4*>(pb + c * 1024 + lane * 16);
      f32x4 rA1 = *reinterpret_cast<const f32x4*>(pb + 4096 + c * 1024 + lane * 16);
      f32x4 rB0 = *reinterpret_cast<const f32x4*>(pb + 8192 + c * 1024 + lane * 16);
      f32x4 rB1 = *reinterpret_cast<const f32x4*>(pb + 12288 + c * 1024 + lane * 16);
#pragma unroll
      for (int i = 0; i < 4; ++i) {
        oA0[4 * c + i] += rA0[i]; oA1[4 * c + i] += rA1[i];
        oB0[4 * c + i] += rB0[i]; oB1[4 * c + i] += rB1[i];
      }
    }
    float LA = xhalf_sum(LpA) +
               *reinterpret_cast<const float*>(smem + 65536 + (ws * 64 + ql) * 4);
    float LB = xhalf_sum(LpB) +
               *reinterpret_cast<const float*>(smem + 65536 + (ws * 64 + 32 + ql) * 4);
    float invA = 1.0f / LA, invB = 1.0f / LB;
#pragma unroll
    for (int r = 0; r < 16; ++r) {
      oA0[r] *= invA; oA1[r] *= invA; oB0[r] *= invB; oB1[r] *= invB;
    }
#pragma unroll
    for (int X = 0; X < 2; ++X) {
      const int wb = ws * 16384 + X * 4096;
      const int qX = q0 + X * 32;
#pragma unroll
      for (int c = 0; c < 4; ++c) {
        float e00 = X ? oB0[4 * c + 0] : oA0[4 * c + 0];
        float e01 = X ? oB0[4 * c + 1] : oA0[4 * c + 1];
        float e02 = X ? oB0[4 * c + 2] : oA0[4 * c + 2];
        float e03 = X ? oB0[4 * c + 3] : oA0[4 * c + 3];
        float e10 = X ? oB1[4 * c + 0] : oA1[4 * c + 0];
        float e11 = X ? oB1[4 * c + 1] : oA1[4 * c + 1];
        float e12 = X ? oB1[4 * c + 2] : oA1[4 * c + 2];
        float e13 = X ? oB1[4 * c + 3] : oA1[4 * c + 3];
        {
          u32 w0 = pkbf(e00, e01), w1 = pkbf(e02, e03);
          int d0 = 8 * c + 4 * hi;
          int byte = (wb + ql * 128 + d0 * 2) ^ ((ql & 7) << 4);
          *reinterpret_cast<u32x2*>(smem + byte) = (u32x2){w0, w1};
        }
        {
          u32 w0 = pkbf(e10, e11), w1 = pkbf(e12, e13);
          int d0 = 32 + 8 * c + 4 * hi;
          int byte = (wb + ql * 128 + d0 * 2) ^ ((ql & 7) << 4);
          *reinterpret_cast<u32x2*>(smem + byte) = (u32x2){w0, w1};
        }
      }
      asm volatile("s_waitcnt lgkmcnt(0)" ::: "memory");
      __builtin_amdgcn_sched_barrier(0);
#pragma unroll
      for (int it = 0; it < 4; ++it) {
        int lin = it * 64 + lane;
        int qr = lin >> 3, ch = lin & 7;
        int byte = wb + qr * 128 + ((ch * 16) ^ ((qr & 7) << 4));
        bf16x8 vrow = *reinterpret_cast<const bf16x8*>(smem + byte);
        *reinterpret_cast<bf16x8*>(Op + hbase + (size_t)(qX + qr) * kD + ch * 8) = vrow;
      }
    }
  }
}

// ---------------- host launch ----------------
extern "C" void kernel_launch(void* const* d_in, const int* in_sizes, int n_in,
                              void* d_out, int out_size, void* d_ws, size_t ws_size,
                              hipStream_t stream) {
  (void)in_sizes; (void)n_in; (void)out_size; (void)ws_size;
  const float* q  = (const float*)d_in[0];
  const float* k  = (const float*)d_in[1];
  const float* v  = (const float*)d_in[2];
  const float* wq = (const float*)d_in[3];
  const float* bq = (const float*)d_in[4];
  const float* wk = (const float*)d_in[5];
  const float* bk = (const float*)d_in[6];
  const float* wv = (const float*)d_in[7];
  const float* bv = (const float*)d_in[8];
  const float* wo = (const float*)d_in[9];
  const float* bo = (const float*)d_in[10];
  float* out = (float*)d_out;

  char* ws = (char*)d_ws;
  const size_t MB = 1ull << 20;
  bf16_t* qb   = (bf16_t*)(ws +  0 * MB);
  bf16_t* kb   = (bf16_t*)(ws +  8 * MB);
  bf16_t* vb   = (bf16_t*)(ws + 16 * MB);
  bf16_t* wqkv = (bf16_t*)(ws + 24 * MB);
  bf16_t* wob  = (bf16_t*)(ws + 30 * MB);
  bf16_t* Qp   = (bf16_t*)(ws + 32 * MB);
  bf16_t* Kp   = (bf16_t*)(ws + 40 * MB);
  bf16_t* Vp   = (bf16_t*)(ws + 48 * MB);
  bf16_t* Opb  = (bf16_t*)(ws + 56 * MB);
  bf16_t* VpT  = (bf16_t*)(ws +  0 * MB);  // reuses qb (dead after projection)

  cvt_all<<<dim3(256, 7), 256, 0, stream>>>(q, k, v, wq, wk, wv, wo,
                                            qb, kb, vb, wqkv, wob);

  gemm_qkv<<<dim3(24, 32), 256, 0, stream>>>(qb, kb, vb, wqkv, bq, bk, bv, Qp, Kp, Vp);

  vtranspose<<<dim3(kS / 256, 32), 256, 0, stream>>>(Vp, VpT);

  attn_fwd<<<dim3(256), 512, 0, stream>>>(Qp, Kp, VpT, Opb);

  gemm_out<<<dim3(16, 32), 256, 0, stream>>>(Opb, wob, bo, out);
}